// Round 9
// baseline (191.384 us; speedup 1.0000x reference)
//
#include <hip/hip_runtime.h>
#include <math.h>

#define NPART 4096
#define NBLK  512   // producer blocks
#define NTHR  256
#define IPB   8     // particles (i) per producer block
#define CAP2  128   // per-block pair-list region (expected ~26, central ~52)
#define MAGIC 0x5A5Au

// Constants, rounded exactly as the reference's weak-typed doubles -> f32
constexpr float RORC   = (float)(2.5e-5 + 3.15e-6);    // RO + RC
constexpr float RORC2  = RORC * RORC;
constexpr float RRF    = 8e-6f;                        // RR
constexpr float RR2    = RRF * RRF;
constexpr float TWORC  = (float)(2.0 * 3.15e-6);       // 2*RC
constexpr float TWORC2 = TWORC * TWORC;
constexpr float C21RC  = (float)(2.1 * 3.15e-6);       // 2.1*RC
constexpr float RCAND2 = 1.6e-9f;                      // (4e-5)^2 > RORC^2
constexpr float C_ROT  = (float)(0.2 * 25.0 * 0.0028); // dt*Gamma*DR
constexpr float C_RN1  = (float)0.07483314773547883;   // f32(sqrt(2*DR))
constexpr float C_SQDT = (float)0.4472135954999579;    // f32(sqrt(dt))
constexpr float C_TRV  = (float)(0.2 * 5e-7);          // dt*velocity
constexpr float C_HALF = (float)0.7071067811865476;    // f32(sqrt(0.5))
constexpr float C_SQ2T = (float)1.6733200530681511e-07;// f32(sqrt(2*DT_TRANS))
constexpr float EPSF   = 1e-14f;

// ---------------------------------------------------------------------------
// Single kernel, 513 blocks x 256 thr.
//   blocks 0..511 : R8 producer (pair sums + mean + epilogue + pair list),
//                   then release-store flag = (MAGIC<<16)|count.
//   block  512    : consumer — acquire-poll all 512 flags, scan counts,
//                   compact pair lists, 3 Gauss-Seidel collision passes.
// One-way dependency only (no grid barrier): producers never wait.
// ---------------------------------------------------------------------------
__global__ __launch_bounds__(NTHR) void fused_all(
        const float2* __restrict__ pos, const float2* __restrict__ ori,
        const float* __restrict__ Deltas, const float* __restrict__ rot_noise,
        const float2* __restrict__ trans_noise,
        float2* __restrict__ out, float2* __restrict__ pA,
        unsigned* __restrict__ flags_g, int* __restrict__ pairs_g,
        int* __restrict__ flat_g) {
    __shared__ float4 pp4[NPART / 2];     // 32 KB: producer pos / consumer ppos
    __shared__ float2 pori_s[NPART];      // 32 KB: producer ori
    __shared__ float  sred[5 * NTHR];     // 5 KB: producer red / consumer counts+scan
    __shared__ float  res[5][IPB];
    __shared__ int    lcnt;
    __shared__ int    lpairs[CAP2];       // 512 B

    const int tid = threadIdx.x;

    // =======================================================================
    // CONSUMER (last block)
    // =======================================================================
    if (blockIdx.x == NBLK) {
        float2* ppos  = (float2*)pp4;     // [NPART]
        int*    cnts  = (int*)sred;       // [NBLK]
        int*    scan  = cnts + NBLK;      // [NBLK]

        // 1. poll flags (agent-scope acquire; poison 0xAAAA... never matches)
        for (int b = tid; b < NBLK; b += NTHR) {
            unsigned v;
            do {
                v = __hip_atomic_load(&flags_g[b], __ATOMIC_ACQUIRE,
                                      __HIP_MEMORY_SCOPE_AGENT);
            } while ((v >> 16) != MAGIC);
            int c = (int)(v & 0xFFFFu);
            cnts[b] = (c < CAP2) ? c : CAP2;   // clamp: no OOB even on bad flag
        }
        __syncthreads();

        // 2. positions (written by producers before their flags)
        for (int k = 0; k < NPART / NTHR; ++k)
            ppos[k * NTHR + tid] = pA[k * NTHR + tid];

        // 3. inclusive scan of 512 counts (2 elems/thread, Hillis-Steele)
        scan[tid] = cnts[tid];
        scan[tid + NTHR] = cnts[tid + NTHR];
        __syncthreads();
        for (int off = 1; off < NBLK; off <<= 1) {
            const int a0 = (tid >= off) ? scan[tid - off] : 0;
            const int a1 = (tid + NTHR >= off) ? scan[tid + NTHR - off] : 0;
            __syncthreads();
            scan[tid] += a0;
            scan[tid + NTHR] += a1;
            __syncthreads();
        }
        const int total = scan[NBLK - 1];

        // 4. compact [512][CAP2] regions -> flat_g (coalesced slot sweep)
        for (int k = 0; k < (NBLK * CAP2) / NTHR; ++k) {
            const int e = tid + k * NTHR;
            const int b = e >> 7, l = e & (CAP2 - 1);
            if (l < cnts[b])
                flat_g[scan[b] - cnts[b] + l] = pairs_g[e];
        }
        __syncthreads();                  // single block: L2-visible after drain

        // 5. three Gauss-Seidel collision passes (as R8)
        for (int pass = 0; pass < 3; ++pass) {
            for (int e = tid; e < total; e += NTHR) {
                const int code = flat_g[e];
                const int i = code >> 12;
                const int j = code & (NPART - 1);
                const float2 pi = ppos[i];
                const float2 pj = ppos[j];
                const float dx = pj.x - pi.x, dy = pj.y - pi.y;
                const float r2 = fmaf(dx, dx, dy * dy);
                if (r2 <= TWORC2 && r2 > 0.f) {
                    const float ab = sqrtf(r2);
                    const float s = (C21RC - ab) * 0.5f / ab;
                    const float mx = dx * s, my = dy * s;
                    atomicAdd(&ppos[i].x, -mx);   // ds_add_f32
                    atomicAdd(&ppos[i].y, -my);
                    atomicAdd(&ppos[j].x,  mx);   // antisymmetric partner
                    atomicAdd(&ppos[j].y,  my);
                }
            }
            __syncthreads();
        }
        for (int k = 0; k < NPART / NTHR; ++k)
            out[k * NTHR + tid] = ppos[k * NTHR + tid];   // section 0 = new_p
        return;
    }

    // =======================================================================
    // PRODUCER (blocks 0..511) — identical to R8's fused_main + flag store
    // =======================================================================
    float2* ppos_s = (float2*)pp4;
    if (tid == 0) lcnt = 0;
    const int il   = tid & (IPB - 1);
    const int seg  = tid / IPB;           // 0..31
    const int gi   = blockIdx.x * IPB + il;
    const int base = seg * 128;

    for (int k = 0; k < NPART / NTHR; ++k) {
        const int j = k * NTHR + tid;
        ppos_s[j] = pos[j];
        pori_s[j] = ori[j];
    }
    __syncthreads();

    const float2 pi = ppos_s[gi];
    float nr = 0.f, sx = 0.f, sy = 0.f, oxs = 0.f, oys = 0.f;
    #pragma unroll 4
    for (int t = 0; t < 64; ++t) {
        const int k2 = (t + seg) & 63;    // stagger: conflict-free
        const int j0 = base + 2 * k2;
        const float4 v = pp4[j0 >> 1];    // pos[j0], pos[j0+1]
        const float dx0 = v.x - pi.x, dy0 = v.y - pi.y;
        const float dx1 = v.z - pi.x, dy1 = v.w - pi.y;
        const float r20 = fmaf(dx0, dx0, dy0 * dy0);
        const float r21 = fmaf(dx1, dx1, dy1 * dy1);
        if (r20 <= RCAND2) {              // rare (incl. diagonal)
            const float2 uj = pori_s[j0];
            if (r20 <= RORC2) { oxs += uj.x; oys += uj.y; }   // inside_Ro
            if (r20 > 0.f) {
                if (r20 <= RR2) {
                    const float dt_ = fmaf(dx0, uj.x, dy0 * uj.y);
                    const float cr_ = fmaf(dy0, uj.x, -dx0 * uj.y);
                    if (!((dt_ <= 0.f) && (cr_ >= 0.f))) { nr += 1.f; sx += v.x; sy += v.y; }
                }
                if (gi < j0) {
                    const int slot = atomicAdd(&lcnt, 1);
                    if (slot < CAP2) lpairs[slot] = (gi << 12) | j0;
                }
            }
        }
        if (r21 <= RCAND2) {
            const int j1 = j0 + 1;
            const float2 uj = pori_s[j1];
            if (r21 <= RORC2) { oxs += uj.x; oys += uj.y; }
            if (r21 > 0.f) {
                if (r21 <= RR2) {
                    const float dt_ = fmaf(dx1, uj.x, dy1 * uj.y);
                    const float cr_ = fmaf(dy1, uj.x, -dx1 * uj.y);
                    if (!((dt_ <= 0.f) && (cr_ >= 0.f))) { nr += 1.f; sx += v.z; sy += v.w; }
                }
                if (gi < j1) {
                    const int slot = atomicAdd(&lcnt, 1);
                    if (slot < CAP2) lpairs[slot] = (gi << 12) | j1;
                }
            }
        }
    }
    __syncthreads();                       // lcnt final; LDS reads done
    sred[0 * NTHR + tid] = nr;
    sred[1 * NTHR + tid] = sx;
    sred[2 * NTHR + tid] = sy;
    sred[3 * NTHR + tid] = oxs;
    sred[4 * NTHR + tid] = oys;
    __syncthreads();
    if (tid < 5 * IPB) {                   // same combine order as R1
        const int q = tid / IPB, ii = tid & (IPB - 1);
        float acc = 0.f;
        #pragma unroll
        for (int s = 0; s < 32; ++s) acc += sred[q * NTHR + ii + IPB * s];
        res[q][ii] = acc;
    }
    // flush per-block candidate list to its fixed region
    const int n_l = (lcnt < CAP2) ? lcnt : CAP2;
    for (int e = tid; e < n_l; e += NTHR)
        pairs_g[blockIdx.x * CAP2 + e] = lpairs[e];
    __syncthreads();

    // mean of all positions (n_a == N), same order as R1
    float mx = 0.f, my = 0.f;
    for (int k = 0; k < NPART / NTHR; ++k) {
        const float2 v = ppos_s[k * NTHR + tid];
        mx += v.x; my += v.y;
    }
    sred[tid] = mx; sred[NTHR + tid] = my;
    __syncthreads();
    for (int s = NTHR / 2; s > 0; s >>= 1) {
        if (tid < s) { sred[tid] += sred[tid + s]; sred[NTHR + tid] += sred[NTHR + tid + s]; }
        __syncthreads();
    }
    const float cmx = sred[0]    * (1.f / NPART);
    const float cmy = sred[NTHR] * (1.f / NPART);

    // per-i epilogue (8 threads)
    if (tid < IPB) {
        const int g2 = blockIdx.x * IPB + tid;
        const float2 p = ppos_s[g2];
        const float2 u = pori_s[g2];
        const float nrv = res[0][tid], sxv = res[1][tid], syv = res[2][tid];
        const float osx = res[3][tid], osy = res[4][tid];

        const float inv = 1.f / fmaxf(nrv, 1.f);
        const float sg  = (nrv > 0.f) ? 1.f : 0.f;
        const float Sx = sxv * inv - p.x * sg;
        const float Sy = syv * inv - p.y * sg;
        const float dxv = -Sx, dyv = -Sy;        // d = -S

        const float Psx = cmx - p.x;
        const float Psy = cmy - p.y;

        float sd, cd;
        sincosf(Deltas[0], &sd, &cd);
        const float Lx = Psx * cd - Psy * sd;    // Ps * exp(+i*Delta)
        const float Ly = Psx * sd + Psy * cd;
        const float Rx = Psx * cd + Psy * sd;    // Ps * exp(-i*Delta)
        const float Ry = Psy * cd - Psx * sd;

        const float no  = fmaxf(sqrtf(osx * osx + osy * osy + 1e-30f), EPSF);
        const float nl  = fmaxf(sqrtf(Lx * Lx + Ly * Ly + 1e-30f), EPSF);
        const float nrr = fmaxf(sqrtf(Rx * Rx + Ry * Ry + 1e-30f), EPSF);
        const float csl = (Lx * osx + Ly * osy) / (nl * no);
        const float csr = (Rx * osx + Ry * osy) / (nrr * no);
        const bool left = (csl >= csr);
        const float bx = left ? Lx : Rx;
        const float by = left ? Ly : Ry;

        float cx, cy;
        if (dxv != 0.f || dyv != 0.f)    { cx = dxv; cy = dyv; }
        else if (bx != 0.f || by != 0.f) { cx = bx;  cy = by;  }
        else                             { cx = 1.f; cy = 0.f; }

        const float dt_ = cx * u.x + cy * u.y;
        const float cr_ = cy * u.x - cx * u.y;
        const float sin_t = cr_ / sqrtf(dt_ * dt_ + cr_ * cr_);

        const float ang = C_ROT * sin_t + (rot_noise[g2] * C_RN1) * C_SQDT;
        float sa, ca;
        sincosf(ang, &sa, &ca);
        const float nux = u.x * ca - u.y * sa;
        const float nuy = u.x * sa + u.y * ca;

        const float2 tn = trans_noise[g2];
        const float tvx = C_TRV * u.x + ((tn.x * C_HALF) * C_SQ2T) * C_SQDT;
        const float tvy = C_TRV * u.y + ((tn.y * C_HALF) * C_SQ2T) * C_SQDT;

        out[1 * NPART + g2] = make_float2(nux, nuy);
        out[2 * NPART + g2] = make_float2(osx, osy);
        out[3 * NPART + g2] = make_float2(Lx, Ly);
        out[4 * NPART + g2] = make_float2(Rx, Ry);
        pA[g2] = make_float2(p.x + tvx, p.y + tvy);
    }
    // publish: all block writes (pairs, pA, out) drained by __syncthreads'
    // vmcnt(0); release-store at agent scope writes back this XCD's L2.
    __syncthreads();
    if (tid == 0)
        __hip_atomic_store(&flags_g[blockIdx.x], (MAGIC << 16) | (unsigned)n_l,
                           __ATOMIC_RELEASE, __HIP_MEMORY_SCOPE_AGENT);
}

extern "C" void kernel_launch(void* const* d_in, const int* in_sizes, int n_in,
                              void* d_out, int out_size, void* d_ws, size_t ws_size,
                              hipStream_t stream) {
    const float2* pos = (const float2*)d_in[0];
    const float2* ori = (const float2*)d_in[1];
    const float*  del = (const float*)d_in[2];
    const float*  rn  = (const float*)d_in[3];
    const float2* tn  = (const float2*)d_in[4];

    char* ws = (char*)d_ws;
    float2*   pA    = (float2*)ws;                       // 32 KB
    unsigned* flags = (unsigned*)(ws + 32 * 1024);       // 2 KB
    int*      pairs = (int*)(ws + 34 * 1024);            // 256 KB
    int*      flat  = (int*)(ws + (34 + 256) * 1024);    // 256 KB
    float2*   o2    = (float2*)d_out;                    // [5][N] float2

    fused_all<<<dim3(NBLK + 1), dim3(NTHR), 0, stream>>>(pos, ori, del, rn, tn,
                                                         o2, pA, flags, pairs, flat);
}

// Round 10
// 101.968 us; speedup vs baseline: 1.8769x; 1.8769x over previous
//
#include <hip/hip_runtime.h>
#include <math.h>

#define NPART 4096
#define NBLK  512
#define NTHR  256
#define IPB   8     // particles (i) per block
#define SMAX  512   // max local collision-set size (expected ~60-120)

// Constants, rounded exactly as the reference's weak-typed doubles -> f32
constexpr float RORC   = (float)(2.5e-5 + 3.15e-6);    // RO + RC
constexpr float RORC2  = RORC * RORC;
constexpr float RRF    = 8e-6f;                        // RR
constexpr float RR2    = RRF * RRF;
constexpr float TWORC  = (float)(2.0 * 3.15e-6);       // 2*RC
constexpr float TWORC2 = TWORC * TWORC;
constexpr float C21RC  = (float)(2.1 * 3.15e-6);       // 2.1*RC
constexpr float RCAND2 = 1.6e-9f;                      // (4e-5)^2 >= 3-hop chain span
constexpr float C_ROT  = (float)(0.2 * 25.0 * 0.0028); // dt*Gamma*DR
constexpr float C_RN1  = (float)0.07483314773547883;   // f32(sqrt(2*DR))
constexpr float C_SQDT = (float)0.4472135954999579;    // f32(sqrt(dt))
constexpr float C_TRV  = (float)(0.2 * 5e-7);          // dt*velocity
constexpr float C_HALF = (float)0.7071067811865476;    // f32(sqrt(0.5))
constexpr float C_SQ2T = (float)1.6733200530681511e-07;// f32(sqrt(2*DT_TRANS))
constexpr float EPSF   = 1e-14f;

// ---------------------------------------------------------------------------
// ONE kernel, 512 blocks x 256 thr, fully block-local (no ws, no 2nd launch).
// Block owns 8 i's. Phases:
//   A. stage all (p,u) in LDS; N^2/512 pair scan -> n_r/S-sums/Ro-sums +
//      bitmap of particles within 4e-5 of any own-i (collision set S).
//   B. reductions + compaction of S (|S|~60-120).
//   C. mean(p), per-i epilogue (sections 1..4) -- bit-identical to R1.
//   D. translate S members locally (reference-exact expression), run the 3
//      JACOBI collision passes over SxS in LDS (3-hop chain span ~3e-5 <
//      4e-5, so the local subgraph reproduces the global iteration for the
//      block's own i's), write section 0.
// ---------------------------------------------------------------------------
__global__ __launch_bounds__(NTHR) void fused_all(
        const float2* __restrict__ pos, const float2* __restrict__ ori,
        const float* __restrict__ Deltas, const float* __restrict__ rot_noise,
        const float2* __restrict__ trans_noise, float2* __restrict__ out) {
    __shared__ float4   pp4[NPART / 2];   // 32 KB, positions as float2[NPART]
    __shared__ float2   pori_s[NPART];    // 32 KB, orientations
    __shared__ float    sred[5 * NTHR];   // 5 KB
    __shared__ float    res[5][IPB];
    __shared__ unsigned bmap[NPART / 32]; // 512 B  candidate-set bitmap
    __shared__ int      Sidx[SMAX];       // 2 KB
    __shared__ float2   posS[SMAX];       // 4 KB
    __shared__ int      scnt;
    __shared__ int      iloc[IPB];        // slot of own i within S
    float2* ppos_s = (float2*)pp4;

    const int tid  = threadIdx.x;
    if (tid == 0) scnt = 0;
    if (tid < NPART / 32) bmap[tid] = 0u;
    const int il   = tid & (IPB - 1);
    const int seg  = tid / IPB;           // 0..31
    const int gi   = blockIdx.x * IPB + il;
    const int base = seg * 128;

    // ---- stage pos+ori into LDS ----
    for (int k = 0; k < NPART / NTHR; ++k) {
        const int j = k * NTHR + tid;
        ppos_s[j] = pos[j];
        pori_s[j] = ori[j];
    }
    __syncthreads();

    // ---- A. pairwise phase: 64 iters x 2 j's ----
    const float2 pi = ppos_s[gi];
    float nr = 0.f, sx = 0.f, sy = 0.f, oxs = 0.f, oys = 0.f;
    #pragma unroll 4
    for (int t = 0; t < 64; ++t) {
        const int k2 = (t + seg) & 63;    // stagger: conflict-free
        const int j0 = base + 2 * k2;
        const float4 v = pp4[j0 >> 1];    // pos[j0], pos[j0+1]
        const float dx0 = v.x - pi.x, dy0 = v.y - pi.y;
        const float dx1 = v.z - pi.x, dy1 = v.w - pi.y;
        const float r20 = fmaf(dx0, dx0, dy0 * dy0);
        const float r21 = fmaf(dx1, dx1, dy1 * dy1);
        if (r20 <= RCAND2) {              // rare (incl. diagonal)
            const float2 uj = pori_s[j0];
            if (r20 <= RORC2) { oxs += uj.x; oys += uj.y; }   // inside_Ro
            if (r20 > 0.f) {
                if (r20 <= RR2) {
                    const float dt_ = fmaf(dx0, uj.x, dy0 * uj.y);
                    const float cr_ = fmaf(dy0, uj.x, -dx0 * uj.y);
                    if (!((dt_ <= 0.f) && (cr_ >= 0.f))) { nr += 1.f; sx += v.x; sy += v.y; }
                }
                atomicOr(&bmap[j0 >> 5], 1u << (j0 & 31));
            }
        }
        if (r21 <= RCAND2) {
            const int j1 = j0 + 1;
            const float2 uj = pori_s[j1];
            if (r21 <= RORC2) { oxs += uj.x; oys += uj.y; }
            if (r21 > 0.f) {
                if (r21 <= RR2) {
                    const float dt_ = fmaf(dx1, uj.x, dy1 * uj.y);
                    const float cr_ = fmaf(dy1, uj.x, -dx1 * uj.y);
                    if (!((dt_ <= 0.f) && (cr_ >= 0.f))) { nr += 1.f; sx += v.z; sy += v.w; }
                }
                atomicOr(&bmap[j1 >> 5], 1u << (j1 & 31));
            }
        }
    }
    if (tid < IPB)                         // own i's are always in S
        atomicOr(&bmap[gi >> 5], 1u << (gi & 31));
    __syncthreads();                       // bmap final; LDS reads done
    sred[0 * NTHR + tid] = nr;
    sred[1 * NTHR + tid] = sx;
    sred[2 * NTHR + tid] = sy;
    sred[3 * NTHR + tid] = oxs;
    sred[4 * NTHR + tid] = oys;
    __syncthreads();
    // ---- B. reductions (same combine order as R1) + S-compaction ----
    if (tid < 5 * IPB) {
        const int q = tid / IPB, ii = tid & (IPB - 1);
        float acc = 0.f;
        #pragma unroll
        for (int s = 0; s < 32; ++s) acc += sred[q * NTHR + ii + IPB * s];
        res[q][ii] = acc;
    }
    if (tid >= 64 && tid < 64 + NPART / 32) {   // disjoint threads: no dependency
        const int w = tid - 64;
        unsigned bits = bmap[w];
        while (bits) {
            const int b = __ffs(bits) - 1;
            bits &= bits - 1;
            const int p = w * 32 + b;
            const int slot = atomicAdd(&scnt, 1);
            if (slot < SMAX) {
                Sidx[slot] = p;
                if ((p >> 3) == (int)blockIdx.x) iloc[p & (IPB - 1)] = slot;
            }
        }
    }
    __syncthreads();
    const int nS = (scnt < SMAX) ? scnt : SMAX;

    // ---- C. mean of all positions (n_a == N), same order as R1 ----
    float mx = 0.f, my = 0.f;
    for (int k = 0; k < NPART / NTHR; ++k) {
        const float2 v = ppos_s[k * NTHR + tid];
        mx += v.x; my += v.y;
    }
    sred[tid] = mx; sred[NTHR + tid] = my;
    __syncthreads();
    for (int s = NTHR / 2; s > 0; s >>= 1) {
        if (tid < s) { sred[tid] += sred[tid + s]; sred[NTHR + tid] += sred[NTHR + tid + s]; }
        __syncthreads();
    }
    const float cmx = sred[0]    * (1.f / NPART);
    const float cmy = sred[NTHR] * (1.f / NPART);

    // ---- D1. translate S members (reference-exact expression) ----
    for (int m = tid; m < nS; m += NTHR) {
        const int p = Sidx[m];
        const float2 pp = ppos_s[p];
        const float2 uu = pori_s[p];
        const float2 tn = trans_noise[p];
        posS[m] = make_float2(
            pp.x + (C_TRV * uu.x + ((tn.x * C_HALF) * C_SQ2T) * C_SQDT),
            pp.y + (C_TRV * uu.y + ((tn.y * C_HALF) * C_SQ2T) * C_SQDT));
    }

    // ---- C2. per-i epilogue (8 threads; sections 1..4) ----
    if (tid < IPB) {
        const int g2 = blockIdx.x * IPB + tid;
        const float2 p = ppos_s[g2];
        const float2 u = pori_s[g2];
        const float nrv = res[0][tid], sxv = res[1][tid], syv = res[2][tid];
        const float osx = res[3][tid], osy = res[4][tid];

        const float inv = 1.f / fmaxf(nrv, 1.f);
        const float sg  = (nrv > 0.f) ? 1.f : 0.f;
        const float Sx = sxv * inv - p.x * sg;
        const float Sy = syv * inv - p.y * sg;
        const float dxv = -Sx, dyv = -Sy;        // d = -S

        const float Psx = cmx - p.x;
        const float Psy = cmy - p.y;

        float sd, cd;
        sincosf(Deltas[0], &sd, &cd);
        const float Lx = Psx * cd - Psy * sd;    // Ps * exp(+i*Delta)
        const float Ly = Psx * sd + Psy * cd;
        const float Rx = Psx * cd + Psy * sd;    // Ps * exp(-i*Delta)
        const float Ry = Psy * cd - Psx * sd;

        const float no  = fmaxf(sqrtf(osx * osx + osy * osy + 1e-30f), EPSF);
        const float nl  = fmaxf(sqrtf(Lx * Lx + Ly * Ly + 1e-30f), EPSF);
        const float nrr = fmaxf(sqrtf(Rx * Rx + Ry * Ry + 1e-30f), EPSF);
        const float csl = (Lx * osx + Ly * osy) / (nl * no);
        const float csr = (Rx * osx + Ry * osy) / (nrr * no);
        const bool left = (csl >= csr);
        const float bx = left ? Lx : Rx;
        const float by = left ? Ly : Ry;

        float cx, cy;
        if (dxv != 0.f || dyv != 0.f)    { cx = dxv; cy = dyv; }
        else if (bx != 0.f || by != 0.f) { cx = bx;  cy = by;  }
        else                             { cx = 1.f; cy = 0.f; }

        const float dt_ = cx * u.x + cy * u.y;
        const float cr_ = cy * u.x - cx * u.y;
        const float sin_t = cr_ / sqrtf(dt_ * dt_ + cr_ * cr_);

        const float ang = C_ROT * sin_t + (rot_noise[g2] * C_RN1) * C_SQDT;
        float sa, ca;
        sincosf(ang, &sa, &ca);
        const float nux = u.x * ca - u.y * sa;
        const float nuy = u.x * sa + u.y * ca;

        out[1 * NPART + g2] = make_float2(nux, nuy);
        out[2 * NPART + g2] = make_float2(osx, osy);
        out[3 * NPART + g2] = make_float2(Lx, Ly);
        out[4 * NPART + g2] = make_float2(Rx, Ry);
    }
    __syncthreads();                      // posS complete

    // ---- D2. three local JACOBI collision passes over S ----
    for (int pass = 0; pass < 3; ++pass) {
        float ax[2] = {0.f, 0.f}, ay[2] = {0.f, 0.f};
        float px[2], py[2];
        #pragma unroll
        for (int q = 0; q < 2; ++q) {
            const int m = tid + q * NTHR;
            if (m < nS) { px[q] = posS[m].x; py[q] = posS[m].y; }
        }
        for (int b = 0; b < nS; ++b) {
            const float2 pb = posS[b];    // broadcast read, conflict-free
            #pragma unroll
            for (int q = 0; q < 2; ++q) {
                const int m = tid + q * NTHR;
                if (m < nS) {
                    const float dx = pb.x - px[q], dy = pb.y - py[q];
                    const float r2 = fmaf(dx, dx, dy * dy);
                    if (r2 <= TWORC2 && r2 > 0.f) {   // b==m excluded by r2>0
                        const float ab = sqrtf(r2);
                        const float s = (C21RC - ab) * 0.5f / ab;
                        ax[q] = fmaf(dx, s, ax[q]);
                        ay[q] = fmaf(dy, s, ay[q]);
                    }
                }
            }
        }
        __syncthreads();                  // all reads done (Jacobi)
        #pragma unroll
        for (int q = 0; q < 2; ++q) {
            const int m = tid + q * NTHR;
            if (m < nS) posS[m] = make_float2(px[q] - ax[q], py[q] - ay[q]);
        }
        __syncthreads();
    }
    // ---- section 0: final positions of own 8 i's ----
    if (tid < IPB)
        out[0 * NPART + blockIdx.x * IPB + tid] = posS[iloc[tid]];
}

extern "C" void kernel_launch(void* const* d_in, const int* in_sizes, int n_in,
                              void* d_out, int out_size, void* d_ws, size_t ws_size,
                              hipStream_t stream) {
    const float2* pos = (const float2*)d_in[0];
    const float2* ori = (const float2*)d_in[1];
    const float*  del = (const float*)d_in[2];
    const float*  rn  = (const float*)d_in[3];
    const float2* tn  = (const float2*)d_in[4];
    float2* o2 = (float2*)d_out;          // [5][N] float2
    (void)d_ws; (void)ws_size;

    fused_all<<<dim3(NBLK), dim3(NTHR), 0, stream>>>(pos, ori, del, rn, tn, o2);
}

// Round 11
// 96.230 us; speedup vs baseline: 1.9888x; 1.0596x over previous
//
#include <hip/hip_runtime.h>
#include <math.h>

#define NPART 4096
#define NBLK  512
#define NTHR  256
#define IPB   8     // particles (i) per block
#define CAPL  1024  // per-block (il,j) candidate list (expected ~112)
#define SMAX  512   // max local collision-set size (expected ~70)

// Constants, rounded exactly as the reference's weak-typed doubles -> f32
constexpr float RORC   = (float)(2.5e-5 + 3.15e-6);    // RO + RC
constexpr float RORC2  = RORC * RORC;
constexpr float RRF    = 8e-6f;                        // RR
constexpr float RR2    = RRF * RRF;
constexpr float TWORC  = (float)(2.0 * 3.15e-6);       // 2*RC
constexpr float TWORC2 = TWORC * TWORC;
constexpr float C21RC  = (float)(2.1 * 3.15e-6);       // 2.1*RC
constexpr float RCAND2 = 1.6e-9f;                      // (4e-5)^2 >= 3-hop chain span
constexpr float C_ROT  = (float)(0.2 * 25.0 * 0.0028); // dt*Gamma*DR
constexpr float C_RN1  = (float)0.07483314773547883;   // f32(sqrt(2*DR))
constexpr float C_SQDT = (float)0.4472135954999579;    // f32(sqrt(dt))
constexpr float C_TRV  = (float)(0.2 * 5e-7);          // dt*velocity
constexpr float C_HALF = (float)0.7071067811865476;    // f32(sqrt(0.5))
constexpr float C_SQ2T = (float)1.6733200530681511e-07;// f32(sqrt(2*DT_TRANS))
constexpr float EPSF   = 1e-14f;

// ---------------------------------------------------------------------------
// ONE kernel, 512 blocks x 256 thr, block-local (no ws). vs R10:
//  - hot N^2 scan is positions-only, 4 independent ds_read_b128 per iter
//    (ILP: 16 stalls/thread instead of 64), rare branch only APPENDS (il,j)
//  - orientations NOT staged (LDS 77.8 -> ~46 KB => 3 blocks/CU, all 512
//    blocks co-resident); u_j-dependent sums done in a sparse post-pass
//    over ~112 candidates/block with ori[j] read from L2
//  - D2 Jacobi b-loop unrolled x4 via float4-aliased posS
// ---------------------------------------------------------------------------
__global__ __launch_bounds__(NTHR) void fused_all(
        const float2* __restrict__ pos, const float2* __restrict__ ori,
        const float* __restrict__ Deltas, const float* __restrict__ rot_noise,
        const float2* __restrict__ trans_noise, float2* __restrict__ out) {
    __shared__ float4   pp4[NPART / 2];   // 32 KB, positions as float2[NPART]
    __shared__ float    sred[2 * NTHR];   // 2 KB (mean reduction)
    __shared__ float    res[5][IPB];      // n_r, Sx, Sy, Ox, Oy per own-i
    __shared__ unsigned bmap[NPART / 32]; // 512 B candidate-set bitmap
    __shared__ int      lpairs[CAPL];     // 4 KB  (il<<12)|j candidates
    __shared__ int      Sidx[SMAX];       // 2 KB
    __shared__ float4   posS4[SMAX / 2];  // 4 KB collision-set positions
    __shared__ int      lcnt, scnt;
    __shared__ int      iloc[IPB];
    float2* ppos_s = (float2*)pp4;
    float2* posS   = (float2*)posS4;

    const int tid = threadIdx.x;
    if (tid == 0) { lcnt = 0; scnt = 0; }
    if (tid < 5 * IPB) ((float*)res)[tid] = 0.f;
    if (tid < NPART / 32) bmap[tid] = 0u;
    const int il  = tid & (IPB - 1);
    const int seg = tid / IPB;            // 0..31
    const int gi  = blockIdx.x * IPB + il;

    // ---- stage positions only ----
    for (int k = 0; k < NPART / NTHR; ++k)
        ppos_s[k * NTHR + tid] = pos[k * NTHR + tid];
    __syncthreads();

    // ---- A. N^2 scan, 16 batches x 4 b128 loads (8 j's) ----
    const float2 pi = ppos_s[gi];
    const int base64 = seg * 64;          // pp4-index base for this seg
    for (int tb = 0; tb < 16; ++tb) {
        const int kb = (tb + seg) & 15;   // stagger: conflict-free across segs
        const float4 v0 = pp4[base64 + kb];
        const float4 v1 = pp4[base64 + kb + 16];
        const float4 v2 = pp4[base64 + kb + 32];
        const float4 v3 = pp4[base64 + kb + 48];
        #pragma unroll
        for (int s = 0; s < 4; ++s) {
            const float4 v = (s == 0) ? v0 : (s == 1) ? v1 : (s == 2) ? v2 : v3;
            const int j0 = seg * 128 + 2 * (kb + 16 * s);
            const float dx0 = v.x - pi.x, dy0 = v.y - pi.y;
            const float dx1 = v.z - pi.x, dy1 = v.w - pi.y;
            const float r20 = fmaf(dx0, dx0, dy0 * dy0);
            const float r21 = fmaf(dx1, dx1, dy1 * dy1);
            if (fminf(r20, r21) <= RCAND2) {       // rare (incl. diagonal)
                if (r20 <= RCAND2) {
                    const int slot = atomicAdd(&lcnt, 1);
                    if (slot < CAPL) lpairs[slot] = (il << 12) | j0;
                    atomicOr(&bmap[j0 >> 5], 1u << (j0 & 31));
                }
                if (r21 <= RCAND2) {
                    const int j1 = j0 + 1;
                    const int slot = atomicAdd(&lcnt, 1);
                    if (slot < CAPL) lpairs[slot] = (il << 12) | j1;
                    atomicOr(&bmap[j1 >> 5], 1u << (j1 & 31));
                }
            }
        }
    }
    __syncthreads();                      // lpairs/bmap final

    // ---- B. sparse post-pass (tid<128) + S-compaction (tid>=128) ----
    const int n_l = (lcnt < CAPL) ? lcnt : CAPL;
    if (tid < 128) {
        for (int e = tid; e < n_l; e += 128) {
            const int code = lpairs[e];
            const int jil = code >> 12, j = code & (NPART - 1);
            const float2 pj = ppos_s[j];
            const float2 pi2 = ppos_s[blockIdx.x * IPB + jil];
            const float dx = pj.x - pi2.x, dy = pj.y - pi2.y;
            const float r2 = fmaf(dx, dx, dy * dy);
            if (r2 <= RORC2) {            // inside_Ro (diag included)
                const float2 uj = ori[j]; // L2-resident
                atomicAdd(&res[3][jil], uj.x);
                atomicAdd(&res[4][jil], uj.y);
                if (r2 <= RR2 && r2 > 0.f) {
                    // in_front fails <=> dot<=0 && cross>=0
                    const float dt_ = fmaf(dx, uj.x, dy * uj.y);
                    const float cr_ = fmaf(dy, uj.x, -dx * uj.y);
                    if (!((dt_ <= 0.f) && (cr_ >= 0.f))) {
                        atomicAdd(&res[0][jil], 1.f);
                        atomicAdd(&res[1][jil], pj.x);
                        atomicAdd(&res[2][jil], pj.y);
                    }
                }
            }
        }
    } else {                              // 128 threads, one bmap word each
        const int w = tid - 128;
        unsigned bits = bmap[w];
        while (bits) {
            const int b = __ffs(bits) - 1;
            bits &= bits - 1;
            const int p = w * 32 + b;
            const int slot = atomicAdd(&scnt, 1);
            if (slot < SMAX) {
                Sidx[slot] = p;
                if ((p >> 3) == (int)blockIdx.x) iloc[p & (IPB - 1)] = slot;
            }
        }
    }
    __syncthreads();
    const int nS = (scnt < SMAX) ? scnt : SMAX;

    // ---- D1. translate S members (reference-exact expression) ----
    for (int m = tid; m < nS; m += NTHR) {
        const int p = Sidx[m];
        const float2 pp = ppos_s[p];
        const float2 uu = ori[p];
        const float2 tn = trans_noise[p];
        posS[m] = make_float2(
            pp.x + (C_TRV * uu.x + ((tn.x * C_HALF) * C_SQ2T) * C_SQDT),
            pp.y + (C_TRV * uu.y + ((tn.y * C_HALF) * C_SQ2T) * C_SQDT));
    }

    // ---- C. mean of all positions (n_a == N) ----
    float mx = 0.f, my = 0.f;
    for (int k = 0; k < NPART / NTHR; ++k) {
        const float2 v = ppos_s[k * NTHR + tid];
        mx += v.x; my += v.y;
    }
    sred[tid] = mx; sred[NTHR + tid] = my;
    __syncthreads();
    for (int s = NTHR / 2; s > 0; s >>= 1) {
        if (tid < s) { sred[tid] += sred[tid + s]; sred[NTHR + tid] += sred[NTHR + tid + s]; }
        __syncthreads();
    }
    const float cmx = sred[0]    * (1.f / NPART);
    const float cmy = sred[NTHR] * (1.f / NPART);

    // ---- C2. per-i epilogue (8 threads; sections 1..4) ----
    if (tid < IPB) {
        const int g2 = blockIdx.x * IPB + tid;
        const float2 p = ppos_s[g2];
        const float2 u = ori[g2];
        const float nrv = res[0][tid], sxv = res[1][tid], syv = res[2][tid];
        const float osx = res[3][tid], osy = res[4][tid];

        const float inv = 1.f / fmaxf(nrv, 1.f);
        const float sg  = (nrv > 0.f) ? 1.f : 0.f;
        const float Sx = sxv * inv - p.x * sg;
        const float Sy = syv * inv - p.y * sg;
        const float dxv = -Sx, dyv = -Sy;        // d = -S

        const float Psx = cmx - p.x;
        const float Psy = cmy - p.y;

        float sd, cd;
        sincosf(Deltas[0], &sd, &cd);
        const float Lx = Psx * cd - Psy * sd;    // Ps * exp(+i*Delta)
        const float Ly = Psx * sd + Psy * cd;
        const float Rx = Psx * cd + Psy * sd;    // Ps * exp(-i*Delta)
        const float Ry = Psy * cd - Psx * sd;

        const float no  = fmaxf(sqrtf(osx * osx + osy * osy + 1e-30f), EPSF);
        const float nl  = fmaxf(sqrtf(Lx * Lx + Ly * Ly + 1e-30f), EPSF);
        const float nrr = fmaxf(sqrtf(Rx * Rx + Ry * Ry + 1e-30f), EPSF);
        const float csl = (Lx * osx + Ly * osy) / (nl * no);
        const float csr = (Rx * osx + Ry * osy) / (nrr * no);
        const bool left = (csl >= csr);
        const float bx = left ? Lx : Rx;
        const float by = left ? Ly : Ry;

        float cx, cy;
        if (dxv != 0.f || dyv != 0.f)    { cx = dxv; cy = dyv; }
        else if (bx != 0.f || by != 0.f) { cx = bx;  cy = by;  }
        else                             { cx = 1.f; cy = 0.f; }

        const float dt_ = cx * u.x + cy * u.y;
        const float cr_ = cy * u.x - cx * u.y;
        const float sin_t = cr_ / sqrtf(dt_ * dt_ + cr_ * cr_);

        const float ang = C_ROT * sin_t + (rot_noise[g2] * C_RN1) * C_SQDT;
        float sa, ca;
        sincosf(ang, &sa, &ca);
        out[1 * NPART + g2] = make_float2(u.x * ca - u.y * sa,
                                          u.x * sa + u.y * ca);
        out[2 * NPART + g2] = make_float2(osx, osy);
        out[3 * NPART + g2] = make_float2(Lx, Ly);
        out[4 * NPART + g2] = make_float2(Rx, Ry);
    }
    __syncthreads();                      // posS complete

    // ---- D2. three local JACOBI passes over S, b-loop unrolled x4 ----
    for (int pass = 0; pass < 3; ++pass) {
        float px[2], py[2], ax[2] = {0.f, 0.f}, ay[2] = {0.f, 0.f};
        bool  mv[2];
        #pragma unroll
        for (int q = 0; q < 2; ++q) {
            const int m = tid + q * NTHR;
            mv[q] = (m < nS);
            if (mv[q]) { px[q] = posS[m].x; py[q] = posS[m].y; }
        }
        int b = 0;
        for (; b + 4 <= nS; b += 4) {
            const float4 w0 = posS4[(b >> 1)];     // entries b, b+1
            const float4 w1 = posS4[(b >> 1) + 1]; // entries b+2, b+3
            const float bxs[4] = {w0.x, w0.z, w1.x, w1.z};
            const float bys[4] = {w0.y, w0.w, w1.y, w1.w};
            #pragma unroll
            for (int s = 0; s < 4; ++s) {
                #pragma unroll
                for (int q = 0; q < 2; ++q) {
                    if (mv[q]) {
                        const float dx = bxs[s] - px[q], dy = bys[s] - py[q];
                        const float r2 = fmaf(dx, dx, dy * dy);
                        if (r2 <= TWORC2 && r2 > 0.f) {
                            const float ab = sqrtf(r2);
                            const float sc = (C21RC - ab) * 0.5f / ab;
                            ax[q] = fmaf(dx, sc, ax[q]);
                            ay[q] = fmaf(dy, sc, ay[q]);
                        }
                    }
                }
            }
        }
        for (; b < nS; ++b) {             // tail
            const float2 pb = posS[b];
            #pragma unroll
            for (int q = 0; q < 2; ++q) {
                if (mv[q]) {
                    const float dx = pb.x - px[q], dy = pb.y - py[q];
                    const float r2 = fmaf(dx, dx, dy * dy);
                    if (r2 <= TWORC2 && r2 > 0.f) {
                        const float ab = sqrtf(r2);
                        const float sc = (C21RC - ab) * 0.5f / ab;
                        ax[q] = fmaf(dx, sc, ax[q]);
                        ay[q] = fmaf(dy, sc, ay[q]);
                    }
                }
            }
        }
        __syncthreads();                  // all reads done (Jacobi)
        #pragma unroll
        for (int q = 0; q < 2; ++q) {
            const int m = tid + q * NTHR;
            if (m < nS) posS[m] = make_float2(px[q] - ax[q], py[q] - ay[q]);
        }
        __syncthreads();
    }
    // ---- section 0: final positions of own 8 i's ----
    if (tid < IPB)
        out[0 * NPART + blockIdx.x * IPB + tid] = posS[iloc[tid]];
}

extern "C" void kernel_launch(void* const* d_in, const int* in_sizes, int n_in,
                              void* d_out, int out_size, void* d_ws, size_t ws_size,
                              hipStream_t stream) {
    const float2* pos = (const float2*)d_in[0];
    const float2* ori = (const float2*)d_in[1];
    const float*  del = (const float*)d_in[2];
    const float*  rn  = (const float*)d_in[3];
    const float2* tn  = (const float2*)d_in[4];
    float2* o2 = (float2*)d_out;          // [5][N] float2
    (void)d_ws; (void)ws_size;

    fused_all<<<dim3(NBLK), dim3(NTHR), 0, stream>>>(pos, ori, del, rn, tn, o2);
}